// Round 3
// baseline (92.705 us; speedup 1.0000x reference)
//
#include <hip/hip_runtime.h>

// CompactBilinearPooling via count-sketch + FFT circular conv (B=256, D=4096, N=16384).
// R11 = R10 + radix-16 inverse: the 4 radix-8 DIT passes (strides 1..2048) are
// regrouped as 3 radix-16 passes I1(S=1)/I2(S=16)/I3(S=256), eliminating one
// full 8192-element LDS round trip (inverse LDS ops 64 -> 48 per-thread-equiv).
// 512 threads x 16 elements per pass; I1->I2 is wave-private (both cover
// positions [1024w,1024w+1024) per wave) so WAVE_FENCE suffices there.
// fft16_dit = fft8_dit pattern extended one stage (ci 0..7, pi/8 roots).
// dur_us = ~83us harness fill floor (2x 256MiB fillBuffer) + kernel share;
// kernel is LDS-issue bound. R10: P4+P5 merged reg-resident 16-pt fwd FFT,
// float4 zero-fill, P5' incremental twiddle. R9: scatter prefetch. R8: b5^d5.
// Structure (R6-verified): two 8192 fwd FFTs via even/odd packing, fused
// unpack+product+pretwiddle pairing, one 8192 inverse + fused radix-2 store.

typedef float v2 __attribute__((ext_vector_type(2)));

#define N1      8192
#define BLOCK   1024
#define DIM     4096
#define PI_F    3.14159265358979323846f
#define RS2     0.70710678118654752f
#define C8      0.92387953251128675f
#define S8      0.38268343236508977f
#define SLOT(e) ((e) ^ (((e) >> 4) & 15))
#define REV13(x) ((int)(__brev((unsigned)(x)) >> 19))
#define WAVE_FENCE() __asm__ volatile("s_waitcnt lgkmcnt(0)" ::: "memory")

static __device__ __forceinline__ v2 cmul(v2 a, v2 b) {
    return a.xx * b + (v2){-a.y, a.y} * b.yx;
}
static __device__ __forceinline__ v2 csqr(v2 a) { return cmul(a, a); }
static __device__ __forceinline__ v2 expi(float phi) {
    float s, c; __sincosf(phi, &s, &c); return (v2){c, s};
}

// Radix-8 DIF (stages 4S,2S,S), r[j] at base+j*S, phi = -pi*k/(4S).
static __device__ __forceinline__ void fft8_dif(v2* r, float phi) {
    v2 W2 = expi(phi), W1 = csqr(W2), W0 = csqr(W1);
    v2 W[3] = {W0, W1, W2};
    #pragma unroll
    for (int p = 2; p >= 0; --p) {
        #pragma unroll
        for (int h = 0; h < 4; ++h) {
            const int jp = h & ((1 << p) - 1);
            const int j  = ((h >> p) << (p + 1)) | jp;
            const int ci = jp << (2 - p);
            v2 Wp = W[p], T;
            if (ci == 0)      T = Wp;
            else if (ci == 2) T = (v2){Wp.y, -Wp.x};            // * (0,-1)
            else if (ci == 1) T = cmul(Wp, (v2){RS2, -RS2});
            else              T = cmul(Wp, (v2){-RS2, -RS2});   // ci==3
            v2 a = r[j], bb = r[j + (1 << p)];
            r[j] = a + bb;
            r[j + (1 << p)] = cmul(a - bb, T);
        }
    }
}

// Radix-16 DIT (stages S,2S,4S,8S), r[j] at base+j*S, phi = +pi*k/(8S), k = base mod S.
static __device__ __forceinline__ void fft16_dit(v2* r, float phi) {
    v2 W3 = expi(phi), W2 = csqr(W3), W1 = csqr(W2), W0 = csqr(W1);
    v2 W[4] = {W0, W1, W2, W3};
    #pragma unroll
    for (int p = 0; p <= 3; ++p) {
        #pragma unroll
        for (int h = 0; h < 8; ++h) {
            const int jp = h & ((1 << p) - 1);
            const int j  = ((h >> p) << (p + 1)) | jp;
            const int ci = jp << (3 - p);
            v2 Wp = W[p], T;
            if (ci == 0)      T = Wp;
            else if (ci == 4) T = (v2){-Wp.y, Wp.x};            // * (0,1)
            else if (ci == 2) T = cmul(Wp, (v2){RS2, RS2});
            else if (ci == 6) T = cmul(Wp, (v2){-RS2, RS2});
            else if (ci == 1) T = cmul(Wp, (v2){C8, S8});
            else if (ci == 3) T = cmul(Wp, (v2){S8, C8});
            else if (ci == 5) T = cmul(Wp, (v2){-S8, C8});
            else              T = cmul(Wp, (v2){-C8, S8});      // ci==7
            v2 a = r[j], bb = cmul(r[j + (1 << p)], T);
            r[j]            = a + bb;
            r[j + (1 << p)] = a - bb;
        }
    }
}

// Radix-16 DIT with k=0 (W=1): pure-constant twiddles.
static __device__ __forceinline__ void fft16_dit0(v2* r) {
    #pragma unroll
    for (int p = 0; p <= 3; ++p) {
        #pragma unroll
        for (int h = 0; h < 8; ++h) {
            const int jp = h & ((1 << p) - 1);
            const int j  = ((h >> p) << (p + 1)) | jp;
            const int ci = jp << (3 - p);
            v2 x = r[j + (1 << p)], bb;
            if (ci == 0)      bb = x;
            else if (ci == 4) bb = (v2){-x.y, x.x};
            else if (ci == 2) bb = cmul(x, (v2){RS2, RS2});
            else if (ci == 6) bb = cmul(x, (v2){-RS2, RS2});
            else if (ci == 1) bb = cmul(x, (v2){C8, S8});
            else if (ci == 3) bb = cmul(x, (v2){S8, C8});
            else if (ci == 5) bb = cmul(x, (v2){-S8, C8});
            else              bb = cmul(x, (v2){-C8, S8});
            v2 a = r[j];
            r[j] = a + bb; r[j + (1 << p)] = a - bb;
        }
    }
}

// Radix-4 DIF (stages 2S,S) on explicit refs, W1 = e^{-i pi k/(2S)}.
static __device__ __forceinline__ void fft4_difW4(v2& r0, v2& r1, v2& r2, v2& r3, v2 W1) {
    v2 W0 = csqr(W1);
    v2 a, bb;
    a = r0; bb = r2; r0 = a + bb; r2 = cmul(a - bb, W1);
    a = r1; bb = r3; r1 = a + bb;
    { v2 d = a - bb; r3 = cmul(d, (v2){W1.y, -W1.x}); }         // W1*(-i)
    a = r0; bb = r1; r0 = a + bb; r1 = cmul(a - bb, W0);
    a = r2; bb = r3; r2 = a + bb; r3 = cmul(a - bb, W0);
}
// Radix-4 DIF, k = 0 (no twiddles), explicit refs.
static __device__ __forceinline__ void fft4_dif04(v2& r0, v2& r1, v2& r2, v2& r3) {
    v2 a, bb;
    a = r0; bb = r2; r0 = a + bb; r2 = a - bb;
    a = r1; bb = r3; r1 = a + bb;
    { v2 d = a - bb; r3 = (v2){d.y, -d.x}; }
    a = r0; bb = r1; r0 = a + bb; r1 = a - bb;
    a = r2; bb = r3; r2 = a + bb; r3 = a - bb;
}

// Fused rfft-unpack + product + irfft-pretwiddle (R6-verified formulas).
static __device__ __forceinline__ void pair_slot(v2* zz, int j) {
    const int k  = REV13(j);
    const int kp = (N1 - k) & (N1 - 1);
    const int j2 = REV13(kp);
    v2 A = zz[SLOT(j)], B = zz[SLOT(j2)];
    v2 C = zz[N1 + SLOT(j)], D = zz[N1 + SLOT(j2)];
    v2 E  = (v2){0.5f * (A.x + B.x),  0.5f * (A.y - B.y)};
    v2 O  = (v2){0.5f * (A.y + B.y), -0.5f * (A.x - B.x)};
    v2 F  = (v2){0.5f * (C.x + D.x),  0.5f * (C.y - D.y)};
    v2 Ov = (v2){0.5f * (C.y + D.y), -0.5f * (C.x - D.x)};
    v2 Tm = expi(-PI_F * (float)k * (1.f / 8192.f));
    v2 u = cmul(Tm, O), v = cmul(Tm, Ov);
    v2 G = cmul(E + u, F + v);
    v2 H = cmul(E - u, F - v);
    v2 S  = (v2){0.5f * (G.x + H.x), 0.5f * (G.y + H.y)};
    v2 gh = G - H;
    v2 t2 = cmul((v2){Tm.x, -Tm.y}, gh);
    v2 Dv = (v2){-0.5f * t2.y, 0.5f * t2.x};
    zz[SLOT(j)]  = S + Dv;
    zz[SLOT(j2)] = (v2){S.x - Dv.x, -(S.y - Dv.y)};
}

__launch_bounds__(BLOCK, 4)
__global__ void cbp_fft_kernel(const float* __restrict__ x1,
                               const float* __restrict__ x2,
                               const int* __restrict__ h1,
                               const float* __restrict__ s1,
                               float* __restrict__ out) {
    __shared__ v2 zz[2 * N1];   // c1 | c2, 128 KB
    const int tid = threadIdx.x;
    const int l   = tid & 63;
    const int b   = blockIdx.x;
    float* zf = (float*)zz;

    // ---- prefetch scatter operands (overlap HBM latency with LDS zeroing) ----
    const float* x1r = x1 + (size_t)b * DIM;
    const float* x2r = x2 + (size_t)b * DIM;
    float sv[DIM / BLOCK], a1[DIM / BLOCK], a2[DIM / BLOCK];
    int   hv[DIM / BLOCK];
    #pragma unroll
    for (int i = 0; i < DIM / BLOCK; ++i) {
        int d = tid + (i << 10);
        sv[i] = s1[d];
        hv[i] = h1[d];
        a1[i] = x1r[d];
        a2[i] = x2r[d];
    }

    // ---- zero both sketches via float4 (global loads in flight above) ----
    {
        float4* z4 = (float4*)zz;       // 8192 float4 total
        #pragma unroll
        for (int j = 0; j < 8; ++j) z4[tid + (j << 10)] = make_float4(0.f, 0.f, 0.f, 0.f);
    }
    __syncthreads();

    // ---- count-sketch scatter (random buckets: full SLOT) ----
    #pragma unroll
    for (int i = 0; i < DIM / BLOCK; ++i) {
        int  h  = hv[i];
        int  fi = (SLOT(h >> 1) << 1) | (h & 1);
        atomicAdd(&zf[fi], sv[i] * a1[i]);
        atomicAdd(&zf[2 * N1 + fi], sv[i] * a2[i]);
    }
    __syncthreads();

    // ======== forward: two independent 8192-pt DIF FFTs ========
    const int half = tid >> 9;
    const int tt   = tid & 511;
    const int hw   = tt >> 6;        // half-wave index 0..7
    v2* Ah = zz + half * N1;

    // P1 (S=1024): slot(k + j*1024) = (k ^ ((k>>4)&15)) + j*1024
    #pragma unroll 1
    for (int q = 0; q < 2; ++q) {
        int k  = tt + (q << 9);
        int bs = k ^ ((k >> 4) & 15);
        v2 r[8];
        #pragma unroll
        for (int j = 0; j < 8; ++j) r[j] = Ah[bs + (j << 10)];
        fft8_dif(r, (float)k * (-PI_F / 4096.f));
        #pragma unroll
        for (int j = 0; j < 8; ++j) Ah[bs + (j << 10)] = r[j];
    }
    __syncthreads();

    // P2 (S=128, wave-private): slot = (bE ^ 8*(j&1)) + 128j
    #pragma unroll 1
    for (int q = 0; q < 2; ++q) {
        int kk = (tt & 63) + (q << 6);
        int bE = ((hw << 10) + kk) ^ (kk >> 4);
        int bO = bE ^ 8;
        v2 r[8];
        #pragma unroll
        for (int j = 0; j < 8; ++j) r[j] = Ah[((j & 1) ? bO : bE) + (j << 7)];
        fft8_dif(r, (float)kk * (-PI_F / 512.f));
        #pragma unroll
        for (int j = 0; j < 8; ++j) Ah[((j & 1) ? bO : bE) + (j << 7)] = r[j];
    }
    WAVE_FENCE();

    // P3 (S=16, wave-private, conflict-free): slot = (a0 ^ j) + 16j
    #pragma unroll 1
    for (int q = 0; q < 2; ++q) {
        int g  = (hw << 3) + ((l >> 4) << 1) + q;
        int kf = l & 15;
        int a0 = (g << 7) + (kf ^ (q << 3));
        v2 r[8];
        #pragma unroll
        for (int j = 0; j < 8; ++j) r[j] = Ah[(a0 ^ j) + (j << 4)];
        fft8_dif(r, (float)kf * (-PI_F / 64.f));
        #pragma unroll
        for (int j = 0; j < 8; ++j) Ah[(a0 ^ j) + (j << 4)] = r[j];
    }
    WAVE_FENCE();

    // P4+P5 merged: register-resident 16-pt FFT on thread-private span.
    // slot(span*16+m) = sbase ^ m; P4 group (stride 4) = R[k4+4j],
    // P5 group (stride 1) = R[4q+j]. One read pass + one write pass.
    {
        const int span  = (hw << 6) + (l & 15) + ((l >> 4) << 4);
        const int sbase = (span << 4) + (span & 15);
        v2 R[16];
        #pragma unroll
        for (int m = 0; m < 16; ++m) R[m] = Ah[sbase ^ m];
        // P4: radix-4 stride 4, W1 = e^{-i pi k4/8} via selects
        #pragma unroll
        for (int k4 = 0; k4 < 4; ++k4) {
            float c = (k4 & 1) ? ((k4 & 2) ? 0.38268343f : 0.92387953f)
                               : ((k4 & 2) ? 0.70710678f : 1.f);
            float s = (k4 & 1) ? ((k4 & 2) ? -0.92387953f : -0.38268343f)
                               : ((k4 & 2) ? -0.70710678f : 0.f);
            fft4_difW4(R[k4], R[k4 + 4], R[k4 + 8], R[k4 + 12], (v2){c, s});
        }
        // P5: radix-4 stride 1, no twiddle
        #pragma unroll
        for (int q = 0; q < 4; ++q)
            fft4_dif04(R[4 * q], R[4 * q + 1], R[4 * q + 2], R[4 * q + 3]);
        #pragma unroll
        for (int m = 0; m < 16; ++m) Ah[sbase ^ m] = R[m];
    }
    __syncthreads();

    // ======== fused pairing (R6-verified) ========
    #pragma unroll 2
    for (int i = 0; i < 4; ++i) pair_slot(zz, (tid + (i << 10)) << 1);
    if (tid == 0) pair_slot(zz, 1);   // k = 4096 self-pair position
    __syncthreads();

    // ======== inverse: one 8192-pt DIT IFFT, radix-16 (3 passes) ========
    // I1 (S=1, k=0): thread t<512 owns positions [t*16, t*16+16);
    // slot(t*16+i) = (t*16+i) ^ (t&15) = Sb ^ i, Sb = (t<<4)|(t&15).
    if (tid < 512) {
        const int Sb = (tid << 4) + (tid & 15);
        v2 r[16];
        #pragma unroll
        for (int i = 0; i < 16; ++i) r[i] = zz[Sb ^ i];
        fft16_dit0(r);
        #pragma unroll
        for (int i = 0; i < 16; ++i) zz[Sb ^ i] = r[i];
    }
    WAVE_FENCE();   // I1->I2 wave-private: both cover positions [1024w, 1024w+1024)

    // I2 (S=16): g = t>>4, k = t&15; positions g*256 + k + 16j;
    // slot = g*256 + 16j + (k^j); phi = +pi*k/128.
    if (tid < 512) {
        const int g = tid >> 4, k = tid & 15;
        const int Bz = g << 8;
        v2 r[16];
        #pragma unroll
        for (int j = 0; j < 16; ++j) r[j] = zz[Bz + (j << 4) + (k ^ j)];
        fft16_dit(r, (float)k * (PI_F / 128.f));
        #pragma unroll
        for (int j = 0; j < 16; ++j) zz[Bz + (j << 4) + (k ^ j)] = r[j];
    }
    __syncthreads();

    // I3 (S=256): g = t>>8, k = t&255; positions g*4096 + k + 256j;
    // slot = (g<<12) + (k&0xF0) + ((k&15)^(k>>4)) + 256j; phi = +pi*k/2048.
    if (tid < 512) {
        const int g = tid >> 8, k = tid & 255;
        const int C = (g << 12) + (k & 0xF0) + ((k & 15) ^ (k >> 4));
        v2 r[16];
        #pragma unroll
        for (int j = 0; j < 16; ++j) r[j] = zz[C + (j << 8)];
        fft16_dit(r, (float)k * (PI_F / 2048.f));
        #pragma unroll
        for (int j = 0; j < 16; ++j) zz[C + (j << 8)] = r[j];
    }
    __syncthreads();

    // P5': final radix-2 + coalesced float4 stores.
    // slot(tid*4+d) = b5 ^ d (XOR!); slot(n+4096) = slot(n) + 4096.
    // Twiddle T(n) = e^{+i pi n/4096} via one sincos + incremental rotation.
    {
        float* outr = out + (size_t)b * (2 * N1);
        const float inv_n1 = 1.0f / (float)N1;
        const int b5 = (tid << 2) ^ ((tid >> 2) & 15);
        v2 Tn = expi(PI_F * (float)(tid << 2) * (1.f / 4096.f));
        const v2 STEP = (v2){0.99999970586288f, 7.6699031874270e-4f}; // e^{i pi/4096}
        v2 lo[4], hi[4];
        #pragma unroll
        for (int d5 = 0; d5 < 4; ++d5) {
            v2 a  = zz[b5 ^ d5];
            v2 bb = zz[(b5 ^ d5) + 4096];
            v2 tb = cmul(Tn, bb);
            lo[d5] = a + tb;
            hi[d5] = a - tb;
            if (d5 < 3) Tn = cmul(Tn, STEP);
        }
        float4 vlo0 = make_float4(lo[0].x * inv_n1, lo[0].y * inv_n1,
                                  lo[1].x * inv_n1, lo[1].y * inv_n1);
        float4 vlo1 = make_float4(lo[2].x * inv_n1, lo[2].y * inv_n1,
                                  lo[3].x * inv_n1, lo[3].y * inv_n1);
        float4 vhi0 = make_float4(hi[0].x * inv_n1, hi[0].y * inv_n1,
                                  hi[1].x * inv_n1, hi[1].y * inv_n1);
        float4 vhi1 = make_float4(hi[2].x * inv_n1, hi[2].y * inv_n1,
                                  hi[3].x * inv_n1, hi[3].y * inv_n1);
        *(float4*)(outr + (tid << 3))          = vlo0;
        *(float4*)(outr + (tid << 3) + 4)      = vlo1;
        *(float4*)(outr + N1 + (tid << 3))     = vhi0;
        *(float4*)(outr + N1 + (tid << 3) + 4) = vhi1;
    }
}

extern "C" void kernel_launch(void* const* d_in, const int* in_sizes, int n_in,
                              void* d_out, int out_size, void* d_ws, size_t ws_size,
                              hipStream_t stream) {
    const float* x1 = (const float*)d_in[0];
    const float* x2 = (const float*)d_in[1];
    const int*   h1 = (const int*)d_in[2];
    const float* s1 = (const float*)d_in[3];
    float* out = (float*)d_out;
    const int B = in_sizes[0] / DIM;   // 256
    cbp_fft_kernel<<<B, BLOCK, 0, stream>>>(x1, x2, h1, s1, out);
}